// Round 1
// baseline (387.119 us; speedup 1.0000x reference)
//
#include <hip/hip_runtime.h>
#include <hip/hip_bf16.h>

// Problem constants
#define BATCH 16384
#define F1    1024
#define F2    512
#define NCLS  64
#define NEXP  8
#define MT    64                 // row tile
#define BPAD  (BATCH + NEXP*MT)  // 16896 (each expert segment padded to x64)
#define NBLKM (BPAD / MT)        // 264

typedef __attribute__((ext_vector_type(8))) short short8;   // 8 bf16 (4 VGPRs)
typedef __attribute__((ext_vector_type(4))) float float4v;  // MFMA C/D

// Workspace layout (bytes)
#define O_META   0            // counts[8], cursors[8], poff[8]
#define O_BEXP   128          // int[264]
#define O_ORDER  1280         // int[16896]
#define O_W1HI   68864        // bf16[8][512][1024]  (W1 transposed: [e][n][k])
#define O_W1LO   (O_W1HI + 8388608)
#define O_W2HI   (O_W1LO + 8388608)   // bf16[8][64][512]  ([e][c][f2])
#define O_W2LO   (O_W2HI + 524288)
#define O_HHI    (O_W2LO + 524288)    // bf16[16896][512]
#define O_HLO    (O_HHI + 17301504)
// total = 52,497,664 bytes

__device__ inline short bf16_rn(float f) {
    unsigned u = __builtin_bit_cast(unsigned, f);
    u = (u + 0x7fffu + ((u >> 16) & 1u)) >> 16;
    return (short)u;
}
__device__ inline float bf16_up(short h) {
    return __builtin_bit_cast(float, ((unsigned)(unsigned short)h) << 16);
}
__device__ inline void split2(float v, short& hi, short& lo) {
    hi = bf16_rn(v);
    lo = bf16_rn(v - bf16_up(hi));
}
__device__ inline float4v mfma16(short8 a, short8 b, float4v c) {
    return __builtin_amdgcn_mfma_f32_16x16x32_bf16(a, b, c, 0, 0, 0);
}

// ---------------- prep kernels ----------------

__global__ void dael_init(int* meta, int* order) {
    int i = blockIdx.x * 256 + threadIdx.x;
    if (i < BPAD) order[i] = -1;
    if (blockIdx.x == 0 && threadIdx.x < 16) meta[threadIdx.x] = 0; // counts+cursors
}

__global__ void dael_count(const int* __restrict__ domain, int* meta) {
    int i = blockIdx.x * 256 + threadIdx.x;
    if (i < BATCH) atomicAdd(&meta[domain[i]], 1);
}

__global__ void dael_plan(const int* __restrict__ meta_in, int* meta, int* bexp) {
    int cnt[NEXP];
    for (int e = 0; e < NEXP; ++e) cnt[e] = meta_in[e];
    // block offsets (in units of 64-row blocks)
    int nb[NEXP], off[NEXP];
    int acc = 0;
    for (int e = 0; e < NEXP; ++e) { nb[e] = (cnt[e] + MT - 1) / MT; off[e] = acc; acc += nb[e]; }
    if (threadIdx.x == 0) {
        for (int e = 0; e < NEXP; ++e) meta[16 + e] = off[e] * MT;  // padded row offset
    }
    for (int i = threadIdx.x; i < NBLKM; i += 256) {
        int ee = -1;
        for (int e = 0; e < NEXP; ++e)
            if (i >= off[e] && i < off[e] + nb[e]) ee = e;
        bexp[i] = ee;
    }
}

__global__ void dael_scatter(const int* __restrict__ domain, int* meta, int* order) {
    int i = blockIdx.x * 256 + threadIdx.x;
    if (i < BATCH) {
        int e = domain[i];
        int pos = meta[16 + e] + atomicAdd(&meta[8 + e], 1);
        order[pos] = i;
    }
}

// ---------------- weight transpose + bf16 split ----------------
// W1[e][k][n] (f32) -> W1T_{hi,lo}[e][n][k] (bf16)
__global__ void dael_convw1(const float* __restrict__ W1, short* w1hi, short* w1lo) {
    __shared__ float tile[32][33];
    const int e = blockIdx.z, k0 = blockIdx.x * 32, n0 = blockIdx.y * 32;
    const int c = threadIdx.x & 31, r0 = threadIdx.x >> 5;
    #pragma unroll
    for (int i = 0; i < 4; ++i) {
        int r = r0 + i * 8;
        tile[r][c] = W1[((size_t)(e * F1 + k0 + r)) * F2 + n0 + c];
    }
    __syncthreads();
    #pragma unroll
    for (int i = 0; i < 4; ++i) {
        int r = r0 + i * 8;                       // n offset
        float v = tile[c][r];                     // W1[e][k0+c][n0+r]
        size_t off = ((size_t)(e * F2 + n0 + r)) * F1 + k0 + c;
        short hi, lo; split2(v, hi, lo);
        w1hi[off] = hi; w1lo[off] = lo;
    }
}

// W2[e][f][c] (f32) -> W2T_{hi,lo}[e][c][f] (bf16)
__global__ void dael_convw2(const float* __restrict__ W2, short* w2hi, short* w2lo) {
    __shared__ float tile[32][33];
    const int e = blockIdx.z, k0 = blockIdx.x * 32, n0 = blockIdx.y * 32;
    const int c = threadIdx.x & 31, r0 = threadIdx.x >> 5;
    #pragma unroll
    for (int i = 0; i < 4; ++i) {
        int r = r0 + i * 8;
        tile[r][c] = W2[((size_t)(e * F2 + k0 + r)) * NCLS + n0 + c];
    }
    __syncthreads();
    #pragma unroll
    for (int i = 0; i < 4; ++i) {
        int r = r0 + i * 8;
        float v = tile[c][r];
        size_t off = ((size_t)(e * NCLS + n0 + r)) * F2 + k0 + c;
        short hi, lo; split2(v, hi, lo);
        w2hi[off] = hi; w2lo[off] = lo;
    }
}

// ---------------- GEMM1: h = relu(x @ W1[e] + b1[e]), split-bf16 MFMA ----------------
// grid (264, 2), block 256. Block: 64 rows x 256 cols, K=1024, BK=32.
__global__ __launch_bounds__(256)
void dael_gemm1(const int* __restrict__ order, const int* __restrict__ bexp,
                const float* __restrict__ x,
                const short* __restrict__ w1hi, const short* __restrict__ w1lo,
                const float* __restrict__ b1,
                short* __restrict__ h_hi, short* __restrict__ h_lo) {
    const int mblk = blockIdx.x;
    const int e = bexp[mblk];
    if (e < 0) return;
    const int n0 = blockIdx.y * 256;
    const int p0 = mblk * MT;
    const int tid = threadIdx.x;
    const int lane = tid & 63, wv = tid >> 6;
    const int quad = lane >> 4, lrow = lane & 15;

    __shared__ __align__(16) short Ahi[64][40], Alo[64][40];
    __shared__ __align__(16) short Bhi[256][40], Blo[256][40];

    float4v acc[4][4];
    const float4v z4 = {0.f, 0.f, 0.f, 0.f};
    #pragma unroll
    for (int i = 0; i < 4; ++i)
        #pragma unroll
        for (int j = 0; j < 4; ++j) acc[i][j] = z4;

    const int sr = tid >> 2;            // 0..63
    const int skk = (tid & 3) * 8;      // 0,8,16,24
    const int samp = order[p0 + sr];
    const float* xrow = (samp >= 0) ? (x + (size_t)samp * F1) : nullptr;
    const short* bh_base = w1hi + (size_t)(e * F2 + n0) * F1;
    const short* bl_base = w1lo + (size_t)(e * F2 + n0) * F1;

    for (int kb = 0; kb < F1 / 32; ++kb) {
        const int k0 = kb * 32;
        __syncthreads();
        // stage A (64x32 f32 -> split bf16)
        {
            float va[8];
            if (xrow) {
                float4 f0 = *(const float4*)(xrow + k0 + skk);
                float4 f1 = *(const float4*)(xrow + k0 + skk + 4);
                va[0] = f0.x; va[1] = f0.y; va[2] = f0.z; va[3] = f0.w;
                va[4] = f1.x; va[5] = f1.y; va[6] = f1.z; va[7] = f1.w;
            } else {
                #pragma unroll
                for (int q = 0; q < 8; ++q) va[q] = 0.f;
            }
            short8 vh, vl;
            #pragma unroll
            for (int q = 0; q < 8; ++q) { short h, l; split2(va[q], h, l); vh[q] = h; vl[q] = l; }
            *(short8*)&Ahi[sr][skk] = vh;
            *(short8*)&Alo[sr][skk] = vl;
        }
        // stage B (256x32 bf16 hi+lo, pre-converted)
        #pragma unroll
        for (int i = 0; i < 4; ++i) {
            const int n = i * 64 + sr;
            const size_t go = (size_t)n * F1 + k0 + skk;
            *(uint4*)&Bhi[n][skk] = *(const uint4*)(bh_base + go);
            *(uint4*)&Blo[n][skk] = *(const uint4*)(bl_base + go);
        }
        __syncthreads();
        // compute
        short8 ah[4], al[4], bh[4], bl[4];
        #pragma unroll
        for (int i = 0; i < 4; ++i) {
            ah[i] = *(const short8*)&Ahi[i * 16 + lrow][quad * 8];
            al[i] = *(const short8*)&Alo[i * 16 + lrow][quad * 8];
        }
        #pragma unroll
        for (int j = 0; j < 4; ++j) {
            bh[j] = *(const short8*)&Bhi[wv * 64 + j * 16 + lrow][quad * 8];
            bl[j] = *(const short8*)&Blo[wv * 64 + j * 16 + lrow][quad * 8];
        }
        #pragma unroll
        for (int i = 0; i < 4; ++i)
            #pragma unroll
            for (int j = 0; j < 4; ++j) {
                acc[i][j] = mfma16(ah[i], bh[j], acc[i][j]);
                acc[i][j] = mfma16(ah[i], bl[j], acc[i][j]);
                acc[i][j] = mfma16(al[i], bh[j], acc[i][j]);
            }
    }
    // epilogue: +b1, relu, split to bf16 hi/lo, store
    const int nbase = n0 + wv * 64;
    #pragma unroll
    for (int j = 0; j < 4; ++j) {
        const int ncol = nbase + j * 16 + lrow;
        const float bb = b1[e * F2 + ncol];
        #pragma unroll
        for (int i = 0; i < 4; ++i)
            #pragma unroll
            for (int r = 0; r < 4; ++r) {
                const int m = i * 16 + quad * 4 + r;
                float hv = fmaxf(acc[i][j][r] + bb, 0.f);
                short hh, hl; split2(hv, hh, hl);
                const size_t off = (size_t)(p0 + m) * F2 + ncol;
                h_hi[off] = hh;
                h_lo[off] = hl;
            }
    }
}

// ---------------- GEMM2: logits = h @ W2[e] + b2[e]; softmax; scatter out ----------------
// grid 264, block 256. Block: 64 rows x 64 classes, K=512, BK=32.
__global__ __launch_bounds__(256)
void dael_gemm2(const int* __restrict__ order, const int* __restrict__ bexp,
                const short* __restrict__ h_hi, const short* __restrict__ h_lo,
                const short* __restrict__ w2hi, const short* __restrict__ w2lo,
                const float* __restrict__ b2, float* __restrict__ out) {
    const int mblk = blockIdx.x;
    const int e = bexp[mblk];
    if (e < 0) return;
    const int p0 = mblk * MT;
    const int tid = threadIdx.x;
    const int lane = tid & 63, wv = tid >> 6;
    const int quad = lane >> 4, lrow = lane & 15;

    __shared__ __align__(16) short Ahi[64][40], Alo[64][40];
    __shared__ __align__(16) short Bhi[64][40], Blo[64][40];
    __shared__ float L[64][68];
    __shared__ float inv[64];

    float4v acc[4];
    const float4v z4 = {0.f, 0.f, 0.f, 0.f};
    #pragma unroll
    for (int i = 0; i < 4; ++i) acc[i] = z4;

    const int sr = tid >> 2;
    const int skk = (tid & 3) * 8;
    const size_t arow = (size_t)(p0 + sr) * F2;
    const size_t brow = (size_t)(e * NCLS + sr) * F2;

    for (int kb = 0; kb < F2 / 32; ++kb) {
        const int k0 = kb * 32;
        __syncthreads();
        *(uint4*)&Ahi[sr][skk] = *(const uint4*)(h_hi + arow + k0 + skk);
        *(uint4*)&Alo[sr][skk] = *(const uint4*)(h_lo + arow + k0 + skk);
        *(uint4*)&Bhi[sr][skk] = *(const uint4*)(w2hi + brow + k0 + skk);
        *(uint4*)&Blo[sr][skk] = *(const uint4*)(w2lo + brow + k0 + skk);
        __syncthreads();
        short8 bh = *(const short8*)&Bhi[wv * 16 + lrow][quad * 8];
        short8 bl = *(const short8*)&Blo[wv * 16 + lrow][quad * 8];
        #pragma unroll
        for (int i = 0; i < 4; ++i) {
            short8 ah = *(const short8*)&Ahi[i * 16 + lrow][quad * 8];
            short8 al = *(const short8*)&Alo[i * 16 + lrow][quad * 8];
            acc[i] = mfma16(ah, bh, acc[i]);
            acc[i] = mfma16(ah, bl, acc[i]);
            acc[i] = mfma16(al, bh, acc[i]);
        }
    }
    // logits -> LDS
    const int n = wv * 16 + lrow;
    const float bb = b2[e * NCLS + n];
    #pragma unroll
    for (int i = 0; i < 4; ++i)
        #pragma unroll
        for (int r = 0; r < 4; ++r) {
            const int m = i * 16 + quad * 4 + r;
            L[m][n] = acc[i][r] + bb;
        }
    __syncthreads();
    // softmax per row (thread t handles row t, t<64)
    if (tid < 64) {
        float mx = -3.402823466e38f;
        #pragma unroll 8
        for (int c = 0; c < NCLS; ++c) mx = fmaxf(mx, L[tid][c]);
        float s = 0.f;
        #pragma unroll 8
        for (int c = 0; c < NCLS; ++c) { float ev = __expf(L[tid][c] - mx); L[tid][c] = ev; s += ev; }
        inv[tid] = 1.f / s;
    }
    __syncthreads();
    // coalesced scatter to out
    const int r = tid >> 2;
    const int cs = (tid & 3) * 16;
    const int samp = order[p0 + r];
    if (samp >= 0) {
        const float sc = inv[r];
        #pragma unroll
        for (int q = 0; q < 4; ++q) {
            float4 v = *(const float4*)&L[r][cs + q * 4];
            v.x *= sc; v.y *= sc; v.z *= sc; v.w *= sc;
            *(float4*)(out + (size_t)samp * NCLS + cs + q * 4) = v;
        }
    }
}

extern "C" void kernel_launch(void* const* d_in, const int* in_sizes, int n_in,
                              void* d_out, int out_size, void* d_ws, size_t ws_size,
                              hipStream_t stream) {
    const int*   domain = (const int*)d_in[0];
    const float* x      = (const float*)d_in[1];
    const float* W1     = (const float*)d_in[2];
    const float* b1     = (const float*)d_in[3];
    const float* W2     = (const float*)d_in[4];
    const float* b2     = (const float*)d_in[5];
    float* out = (float*)d_out;

    char* ws = (char*)d_ws;
    int*   meta  = (int*)(ws + O_META);
    int*   bexp  = (int*)(ws + O_BEXP);
    int*   order = (int*)(ws + O_ORDER);
    short* w1hi  = (short*)(ws + O_W1HI);
    short* w1lo  = (short*)(ws + O_W1LO);
    short* w2hi  = (short*)(ws + O_W2HI);
    short* w2lo  = (short*)(ws + O_W2LO);
    short* hhi   = (short*)(ws + O_HHI);
    short* hlo   = (short*)(ws + O_HLO);

    dael_init<<<(BPAD + 255) / 256, 256, 0, stream>>>(meta, order);
    dael_count<<<BATCH / 256, 256, 0, stream>>>(domain, meta);
    dael_plan<<<1, 256, 0, stream>>>(meta, meta, bexp);
    dael_scatter<<<BATCH / 256, 256, 0, stream>>>(domain, meta, order);
    dael_convw1<<<dim3(F1 / 32, F2 / 32, NEXP), 256, 0, stream>>>(W1, w1hi, w1lo);
    dael_convw2<<<dim3(F2 / 32, NCLS / 32, NEXP), 256, 0, stream>>>(W2, w2hi, w2lo);
    dael_gemm1<<<dim3(NBLKM, 2), 256, 0, stream>>>(order, bexp, x, w1hi, w1lo, b1, hhi, hlo);
    dael_gemm2<<<NBLKM, 256, 0, stream>>>(order, bexp, hhi, hlo, w2hi, w2lo, b2, out);
}

// Round 2
// 298.272 us; speedup vs baseline: 1.2979x; 1.2979x over previous
//
#include <hip/hip_runtime.h>
#include <hip/hip_bf16.h>

// Problem constants
#define BATCH 16384
#define F1    1024
#define F2    512
#define NCLS  64
#define NEXP  8
#define SEG   128                 // expert segment granularity (= gemm1 BM)
#define BPAD  (BATCH + NEXP*SEG)  // 17408
#define NB1   (BPAD / 128)        // 136 gemm1 m-blocks
#define NB2   (BPAD / 32)         // 544 gemm2 m-blocks

typedef __attribute__((ext_vector_type(8))) short short8;   // 8 bf16
typedef __attribute__((ext_vector_type(4))) float float4v;  // MFMA C/D

// Workspace layout (bytes); total ~120.7 MB
#define O_META   0                        // cursors[8]@8, bases[8]@16
#define O_BEXP   128                      // int[136]
#define O_ORDER  704                      // int[17408]
#define O_ZROW   70336                    // bf16[1024] zeros (pad-row source)
#define O_XHI    72448                    // bf16[16384][1024]
#define O_XLO    (O_XHI + 33554432)
#define O_W1HI   (O_XLO + 33554432)       // bf16[8][512][1024]  [e][n][k]
#define O_W1LO   (O_W1HI + 8388608)
#define O_W2HI   (O_W1LO + 8388608)       // bf16[8][64][512]    [e][c][f2]
#define O_W2LO   (O_W2HI + 524288)
#define O_HHI    (O_W2LO + 524288)        // bf16[17408][512]
#define O_HLO    (O_HHI + 17825792)

__device__ inline short bf16_rn(float f) {
    unsigned u = __builtin_bit_cast(unsigned, f);
    u = (u + 0x7fffu + ((u >> 16) & 1u)) >> 16;
    return (short)u;
}
__device__ inline float bf16_up(short h) {
    return __builtin_bit_cast(float, ((unsigned)(unsigned short)h) << 16);
}
__device__ inline void split2(float v, short& hi, short& lo) {
    hi = bf16_rn(v);
    lo = bf16_rn(v - bf16_up(hi));
}
__device__ inline float4v mfma16(short8 a, short8 b, float4v c) {
    return __builtin_amdgcn_mfma_f32_16x16x32_bf16(a, b, c, 0, 0, 0);
}
__device__ inline void glds16(const void* g, void* l) {
    __builtin_amdgcn_global_load_lds((const __attribute__((address_space(1))) void*)g,
                                     (__attribute__((address_space(3))) void*)l,
                                     16, 0, 0);
}

// ---------------- prep ----------------

__global__ void dael_init(int* order, int* zrow) {
    int i = blockIdx.x * 256 + threadIdx.x;
    if (i < BPAD) order[i] = -1;
    if (i < 512) zrow[i] = 0;
}

// single block: histogram + segment plan + zero cursors + bexp
__global__ void dael_plan(const int* __restrict__ domain, int* meta, int* bexp) {
    __shared__ int sc[NEXP];
    __shared__ int off[NEXP + 1];
    const int tid = threadIdx.x;
    int c[NEXP];
    #pragma unroll
    for (int e = 0; e < NEXP; ++e) c[e] = 0;
    for (int i = tid; i < BATCH; i += 256) {
        int d = domain[i];
        #pragma unroll
        for (int e = 0; e < NEXP; ++e) c[e] += (d == e);
    }
    if (tid < NEXP) sc[tid] = 0;
    __syncthreads();
    #pragma unroll
    for (int e = 0; e < NEXP; ++e) if (c[e]) atomicAdd(&sc[e], c[e]);
    __syncthreads();
    if (tid == 0) {
        int acc = 0;
        for (int e = 0; e < NEXP; ++e) {
            off[e] = acc;
            meta[16 + e] = acc * 128;   // padded row base
            meta[8 + e]  = 0;           // cursor
            acc += (sc[e] + 127) >> 7;
        }
        off[NEXP] = acc;
    }
    __syncthreads();
    for (int i = tid; i < NB1; i += 256) {
        int ee = -1;
        #pragma unroll
        for (int e = 0; e < NEXP; ++e)
            if (i >= off[e] && i < off[e + 1]) ee = e;
        bexp[i] = ee;
    }
}

// per-block LDS ranks: 8 global atomics per block instead of 256
__global__ void dael_scatter(const int* __restrict__ domain, int* meta, int* order) {
    __shared__ int lc[NEXP], lb[NEXP];
    const int tid = threadIdx.x;
    const int i = blockIdx.x * 256 + tid;
    if (tid < NEXP) lc[tid] = 0;
    __syncthreads();
    const int d = domain[i];
    const int r = atomicAdd(&lc[d], 1);
    __syncthreads();
    if (tid < NEXP && lc[tid] > 0) lb[tid] = atomicAdd(&meta[8 + tid], lc[tid]);
    __syncthreads();
    order[meta[16 + d] + lb[d] + r] = i;
}

// x fp32 -> xhi/xlo bf16 planes
__global__ void dael_xsplit(const float* __restrict__ x, short* __restrict__ xhi,
                            short* __restrict__ xlo) {
    const size_t i8 = (size_t)(blockIdx.x * 256 + threadIdx.x) * 8;
    float4 f0 = *(const float4*)(x + i8);
    float4 f1 = *(const float4*)(x + i8 + 4);
    float va[8] = {f0.x, f0.y, f0.z, f0.w, f1.x, f1.y, f1.z, f1.w};
    short8 vh, vl;
    #pragma unroll
    for (int q = 0; q < 8; ++q) { short h, l; split2(va[q], h, l); vh[q] = h; vl[q] = l; }
    *(short8*)(xhi + i8) = vh;
    *(short8*)(xlo + i8) = vl;
}

// W1[e][k][n] f32 -> [e][n][k] bf16 hi/lo
__global__ void dael_convw1(const float* __restrict__ W1, short* w1hi, short* w1lo) {
    __shared__ float tile[32][33];
    const int e = blockIdx.z, k0 = blockIdx.x * 32, n0 = blockIdx.y * 32;
    const int c = threadIdx.x & 31, r0 = threadIdx.x >> 5;
    #pragma unroll
    for (int i = 0; i < 4; ++i) {
        int r = r0 + i * 8;
        tile[r][c] = W1[((size_t)(e * F1 + k0 + r)) * F2 + n0 + c];
    }
    __syncthreads();
    #pragma unroll
    for (int i = 0; i < 4; ++i) {
        int r = r0 + i * 8;
        float v = tile[c][r];
        size_t off = ((size_t)(e * F2 + n0 + r)) * F1 + k0 + c;
        short hi, lo; split2(v, hi, lo);
        w1hi[off] = hi; w1lo[off] = lo;
    }
}

// W2[e][f][c] f32 -> [e][c][f] bf16 hi/lo
__global__ void dael_convw2(const float* __restrict__ W2, short* w2hi, short* w2lo) {
    __shared__ float tile[32][33];
    const int e = blockIdx.z, k0 = blockIdx.x * 32, n0 = blockIdx.y * 32;
    const int c = threadIdx.x & 31, r0 = threadIdx.x >> 5;
    #pragma unroll
    for (int i = 0; i < 4; ++i) {
        int r = r0 + i * 8;
        tile[r][c] = W2[((size_t)(e * F2 + k0 + r)) * NCLS + n0 + c];
    }
    __syncthreads();
    #pragma unroll
    for (int i = 0; i < 4; ++i) {
        int r = r0 + i * 8;
        float v = tile[c][r];
        size_t off = ((size_t)(e * NCLS + n0 + r)) * F2 + k0 + c;
        short hi, lo; split2(v, hi, lo);
        w2hi[off] = hi; w2lo[off] = lo;
    }
}

// ---------------- GEMM1: 128x128 tile, BK=32, fully async staging ----------------
// grid (136,4), 256 threads. LDS tiles [128][32] bf16, XOR-swizzled chunks.
__global__ __launch_bounds__(256)
void dael_gemm1(const int* __restrict__ order, const int* __restrict__ bexp,
                const short* __restrict__ xhi, const short* __restrict__ xlo,
                const short* __restrict__ zrow,
                const short* __restrict__ w1hi, const short* __restrict__ w1lo,
                const float* __restrict__ b1,
                short* __restrict__ hhi, short* __restrict__ hlo) {
    const int e = bexp[blockIdx.x];
    if (e < 0) return;
    const int p0 = blockIdx.x * 128;
    const int n0 = blockIdx.y * 128;
    const int tid = threadIdx.x;
    const int lane = tid & 63, wv = tid >> 6;
    const int quad = lane >> 4, lrow = lane & 15;
    const int r0w = (wv >> 1) * 64, c0w = (wv & 1) * 64;

    __shared__ __align__(16) short SM[17920];  // 35840 B: tiles 32 KB, epilogue [128][140]
    char* SMc = (char*)SM;

    // staging: thread t -> row t>>2, LDS slot t&3, global chunk swizzled
    const int rrel = tid >> 2;
    const int qe = (((tid & 3) ^ ((tid >> 2) & 3) ^ ((tid >> 4) & 3)) << 3);
    const int s0 = order[p0 + rrel], s1 = order[p0 + 64 + rrel];
    const short* a0h = (s0 >= 0 ? xhi + (size_t)s0 * F1 : zrow) + qe;
    const short* a0l = (s0 >= 0 ? xlo + (size_t)s0 * F1 : zrow) + qe;
    const short* a1h = (s1 >= 0 ? xhi + (size_t)s1 * F1 : zrow) + qe;
    const short* a1l = (s1 >= 0 ? xlo + (size_t)s1 * F1 : zrow) + qe;
    const short* b0h = w1hi + (size_t)(e * F2 + n0 + rrel) * F1 + qe;
    const short* b1h_ = b0h + (size_t)64 * F1;
    const short* b0l = w1lo + (size_t)(e * F2 + n0 + rrel) * F1 + qe;
    const short* b1l_ = b0l + (size_t)64 * F1;
    const int soff = tid * 16;

    float4v acc[4][4] = {};
    const int sw = (lrow & 3) ^ ((lrow >> 2) & 3);
    const int slotb = (quad ^ sw) << 4;

    for (int k0 = 0; k0 < F1; k0 += 32) {
        __syncthreads();
        glds16(a0h + k0, SMc + soff);            // A hi rows 0-63
        glds16(a1h + k0, SMc + 4096 + soff);     // A hi rows 64-127
        glds16(a0l + k0, SMc + 8192 + soff);     // A lo
        glds16(a1l + k0, SMc + 12288 + soff);
        glds16(b0h + k0, SMc + 16384 + soff);    // B hi rows 0-63
        glds16(b1h_ + k0, SMc + 20480 + soff);
        glds16(b0l + k0, SMc + 24576 + soff);    // B lo
        glds16(b1l_ + k0, SMc + 28672 + soff);
        __syncthreads();
        short8 ah[4], al[4], bh[4], bl[4];
        #pragma unroll
        for (int i = 0; i < 4; ++i) {
            const int rb = (r0w + i * 16 + lrow) * 64 + slotb;
            ah[i] = *(const short8*)(SMc + rb);
            al[i] = *(const short8*)(SMc + 8192 + rb);
        }
        #pragma unroll
        for (int j = 0; j < 4; ++j) {
            const int cb = (c0w + j * 16 + lrow) * 64 + slotb;
            bh[j] = *(const short8*)(SMc + 16384 + cb);
            bl[j] = *(const short8*)(SMc + 24576 + cb);
        }
        #pragma unroll
        for (int i = 0; i < 4; ++i)
            #pragma unroll
            for (int j = 0; j < 4; ++j) {
                acc[i][j] = mfma16(ah[i], bh[j], acc[i][j]);
                acc[i][j] = mfma16(ah[i], bl[j], acc[i][j]);
                acc[i][j] = mfma16(al[i], bh[j], acc[i][j]);
            }
    }

    // epilogue: +b1, relu, split; coalesce via LDS transpose [128][140]
    float bv[4];
    #pragma unroll
    for (int j = 0; j < 4; ++j) bv[j] = b1[e * F2 + n0 + c0w + j * 16 + lrow];

    #pragma unroll
    for (int plane = 0; plane < 2; ++plane) {
        __syncthreads();
        #pragma unroll
        for (int i = 0; i < 4; ++i)
            #pragma unroll
            for (int j = 0; j < 4; ++j)
                #pragma unroll
                for (int r = 0; r < 4; ++r) {
                    const int m = r0w + i * 16 + quad * 4 + r;
                    const int n = c0w + j * 16 + lrow;
                    float hv = fmaxf(acc[i][j][r] + bv[j], 0.f);
                    short hi = bf16_rn(hv);
                    short val = plane ? bf16_rn(hv - bf16_up(hi)) : hi;
                    SM[m * 140 + n] = val;
                }
        __syncthreads();
        short* dst = plane ? hlo : hhi;
        const int row = tid >> 1, half = tid & 1;
        #pragma unroll
        for (int s = 0; s < 8; ++s) {
            short8 v = *(const short8*)(SMc + (row * 140 + half * 64 + s * 8) * 2);
            *(short8*)(dst + (size_t)(p0 + row) * F2 + n0 + half * 64 + s * 8) = v;
        }
    }
}

// ---------------- GEMM2: 32 rows x 64 classes, BK=64, async staging; softmax ----------------
// grid 544, 256 threads.
__global__ __launch_bounds__(256)
void dael_gemm2(const int* __restrict__ order, const int* __restrict__ bexp,
                const short* __restrict__ hhi, const short* __restrict__ hlo,
                const short* __restrict__ w2hi, const short* __restrict__ w2lo,
                const float* __restrict__ b2, float* __restrict__ out) {
    const int e = bexp[blockIdx.x >> 2];
    if (e < 0) return;
    const int p0 = blockIdx.x * 32;
    const int tid = threadIdx.x;
    const int lane = tid & 63, wv = tid >> 6;
    const int quad = lane >> 4, lrow = lane & 15;

    __shared__ __align__(16) short SM2[12288]; // 24 KB tiles
    __shared__ float L[32][68];
    __shared__ float inv[32];
    char* SMc = (char*)SM2;

    // staging: thread t -> row t>>3, slot t&7 (rows are 128 B)
    const int rrel = tid >> 3;
    const int qe = (((tid & 7) ^ ((tid >> 3) & 7)) << 3);
    const short* ah_ = hhi + (size_t)(p0 + rrel) * F2 + qe;
    const short* al_ = hlo + (size_t)(p0 + rrel) * F2 + qe;
    const short* b0h = w2hi + (size_t)(e * NCLS + rrel) * F2 + qe;
    const short* b1h_ = b0h + (size_t)32 * F2;
    const short* b0l = w2lo + (size_t)(e * NCLS + rrel) * F2 + qe;
    const short* b1l_ = b0l + (size_t)32 * F2;
    const int soff = tid * 16;

    float4v acc[2] = {};
    const int swb = lrow & 7;

    for (int k0 = 0; k0 < F2; k0 += 64) {
        __syncthreads();
        glds16(ah_ + k0, SMc + soff);            // A hi [32][64]
        glds16(al_ + k0, SMc + 4096 + soff);     // A lo
        glds16(b0h + k0, SMc + 8192 + soff);     // B hi rows 0-31
        glds16(b1h_ + k0, SMc + 12288 + soff);   // B hi rows 32-63
        glds16(b0l + k0, SMc + 16384 + soff);    // B lo
        glds16(b1l_ + k0, SMc + 20480 + soff);
        __syncthreads();
        #pragma unroll
        for (int s = 0; s < 2; ++s) {
            const int slot = (((s * 4 + quad) ^ swb) << 4);
            const int brow = (wv * 16 + lrow) * 128 + slot;
            short8 bhf = *(const short8*)(SMc + 8192 + brow);
            short8 blf = *(const short8*)(SMc + 16384 + brow);
            #pragma unroll
            for (int i = 0; i < 2; ++i) {
                const int arow = (i * 16 + lrow) * 128 + slot;
                short8 ahf = *(const short8*)(SMc + arow);
                short8 alf = *(const short8*)(SMc + 4096 + arow);
                acc[i] = mfma16(ahf, bhf, acc[i]);
                acc[i] = mfma16(ahf, blf, acc[i]);
                acc[i] = mfma16(alf, bhf, acc[i]);
            }
        }
    }

    const int n = wv * 16 + lrow;
    const float bb = b2[e * NCLS + n];
    #pragma unroll
    for (int i = 0; i < 2; ++i)
        #pragma unroll
        for (int r = 0; r < 4; ++r)
            L[i * 16 + quad * 4 + r][n] = acc[i][r] + bb;
    __syncthreads();
    if (tid < 32) {
        float mx = -3.402823466e38f;
        #pragma unroll 8
        for (int c = 0; c < NCLS; ++c) mx = fmaxf(mx, L[tid][c]);
        float s = 0.f;
        #pragma unroll 8
        for (int c = 0; c < NCLS; ++c) { float ev = __expf(L[tid][c] - mx); L[tid][c] = ev; s += ev; }
        inv[tid] = 1.f / s;
    }
    __syncthreads();
    if (tid < 128) {
        const int r = tid >> 2, cs = (tid & 3) * 16;
        const int samp = order[p0 + r];
        if (samp >= 0) {
            const float sc = inv[r];
            #pragma unroll
            for (int q = 0; q < 4; ++q) {
                float4 v = *(const float4*)&L[r][cs + q * 4];
                v.x *= sc; v.y *= sc; v.z *= sc; v.w *= sc;
                *(float4*)(out + (size_t)samp * NCLS + cs + q * 4) = v;
            }
        }
    }
}

extern "C" void kernel_launch(void* const* d_in, const int* in_sizes, int n_in,
                              void* d_out, int out_size, void* d_ws, size_t ws_size,
                              hipStream_t stream) {
    const int*   domain = (const int*)d_in[0];
    const float* x      = (const float*)d_in[1];
    const float* W1     = (const float*)d_in[2];
    const float* b1     = (const float*)d_in[3];
    const float* W2     = (const float*)d_in[4];
    const float* b2     = (const float*)d_in[5];
    float* out = (float*)d_out;

    char* ws = (char*)d_ws;
    int*   meta  = (int*)(ws + O_META);
    int*   bexp  = (int*)(ws + O_BEXP);
    int*   order = (int*)(ws + O_ORDER);
    short* zrow  = (short*)(ws + O_ZROW);
    short* xhi   = (short*)(ws + O_XHI);
    short* xlo   = (short*)(ws + O_XLO);
    short* w1hi  = (short*)(ws + O_W1HI);
    short* w1lo  = (short*)(ws + O_W1LO);
    short* w2hi  = (short*)(ws + O_W2HI);
    short* w2lo  = (short*)(ws + O_W2LO);
    short* hhi   = (short*)(ws + O_HHI);
    short* hlo   = (short*)(ws + O_HLO);

    dael_init<<<(BPAD + 255) / 256, 256, 0, stream>>>(order, (int*)zrow);
    dael_plan<<<1, 256, 0, stream>>>(domain, meta, bexp);
    dael_scatter<<<BATCH / 256, 256, 0, stream>>>(domain, meta, order);
    dael_xsplit<<<(BATCH * F1 / 8) / 256, 256, 0, stream>>>(x, xhi, xlo);
    dael_convw1<<<dim3(F1 / 32, F2 / 32, NEXP), 256, 0, stream>>>(W1, w1hi, w1lo);
    dael_convw2<<<dim3(F2 / 32, NCLS / 32, NEXP), 256, 0, stream>>>(W2, w2hi, w2lo);
    dael_gemm1<<<dim3(NB1, 4), 256, 0, stream>>>(order, bexp, xhi, xlo, zrow,
                                                 w1hi, w1lo, b1, hhi, hlo);
    dael_gemm2<<<NB2, 256, 0, stream>>>(order, bexp, hhi, hlo, w2hi, w2lo, b2, out);
}